// Round 4
// baseline (254.192 us; speedup 1.0000x reference)
//
#include <hip/hip_runtime.h>

#define B_ 4096
#define T_ 256
#define I_ 16
#define H_ 32

typedef _Float16 half2_t __attribute__((ext_vector_type(2)));
typedef _Float16 half4_t __attribute__((ext_vector_type(4)));
typedef _Float16 half8_t __attribute__((ext_vector_type(8)));

union H8 {
    half8_t v;
    half2_t h[4];
};

__device__ __forceinline__ float sigm_(float x) {
    float e = __builtin_amdgcn_exp2f(-1.442695041f * x);
    return __builtin_amdgcn_rcpf(1.0f + e);
}
__device__ __forceinline__ float tanh_(float x) {
    float e = __builtin_amdgcn_exp2f(-2.885390082f * x);
    float r = __builtin_amdgcn_rcpf(1.0f + e);
    return __fmaf_rn(2.0f, r, -1.0f);
}

// One 64-thread block = 1 wave = 1 batch element.
// PyTorch gate rows: [0,32)=i [32,64)=f [64,96)=g [96,128)=o.
// Lane tid owns rows tid (i|f) and tid+64 (g|o):
//   lanes 0-31:  i_j (sigmoid), g_j (tanh)     j = tid
//   lanes 32-63: f_j (sigmoid), o_j (sigmoid)  j = tid-32
// Two shfl_xor(32) exchanges recombine; lanes 0-31 hold c_j/h_j.
// 4096 waves -> 4 waves/SIMD (2x round-3 occupancy), 48 dot2/lane/step
// in 4 independent 12-deep chains.
__global__ __launch_bounds__(64, 4)
void lstm_gate_split(const float* __restrict__ x,
                     const float* __restrict__ Wih,
                     const float* __restrict__ Whh,
                     const float* __restrict__ bih,
                     const float* __restrict__ bhh,
                     const float* __restrict__ Wfc,
                     const float* __restrict__ bfc,
                     float* __restrict__ out)
{
    __shared__ __align__(16) _Float16 hbuf[H_];         // 64 B
    __shared__ __align__(16) _Float16 xbuf[16 * I_];    // 512 B (16 timesteps)

    const int tid  = threadIdx.x;
    const int b    = blockIdx.x;
    const bool lo  = (tid < 32);

    const int rowA = tid;        // gate i (lanes<32) or f (lanes>=32)
    const int rowB = tid + 64;   // gate g (lanes<32) or o (lanes>=32)

    // ---- load + f16-pack the two weight rows ----
    half2_t wA[24], wB[24];      // [0,8)=Wih row, [8,24)=Whh row
#pragma unroll
    for (int k = 0; k < I_ / 4; ++k) {
        const float4 va = *reinterpret_cast<const float4*>(Wih + rowA * I_ + 4 * k);
        wA[2 * k + 0] = half2_t{(_Float16)va.x, (_Float16)va.y};
        wA[2 * k + 1] = half2_t{(_Float16)va.z, (_Float16)va.w};
        const float4 vb = *reinterpret_cast<const float4*>(Wih + rowB * I_ + 4 * k);
        wB[2 * k + 0] = half2_t{(_Float16)vb.x, (_Float16)vb.y};
        wB[2 * k + 1] = half2_t{(_Float16)vb.z, (_Float16)vb.w};
    }
#pragma unroll
    for (int k = 0; k < H_ / 4; ++k) {
        const float4 va = *reinterpret_cast<const float4*>(Whh + rowA * H_ + 4 * k);
        wA[8 + 2 * k + 0] = half2_t{(_Float16)va.x, (_Float16)va.y};
        wA[8 + 2 * k + 1] = half2_t{(_Float16)va.z, (_Float16)va.w};
        const float4 vb = *reinterpret_cast<const float4*>(Whh + rowB * H_ + 4 * k);
        wB[8 + 2 * k + 0] = half2_t{(_Float16)vb.x, (_Float16)vb.y};
        wB[8 + 2 * k + 1] = half2_t{(_Float16)vb.z, (_Float16)vb.w};
    }
    const float biasA = bih[rowA] + bhh[rowA];
    const float biasB = bih[rowB] + bhh[rowB];

    // loop-invariant activation-B coefficients: tanh for lanes<32, sigmoid else
    const float mB   = lo ? -2.885390082f : -1.442695041f;
    const float mulB = lo ? 2.0f : 1.0f;
    const float addB = lo ? -1.0f : 0.0f;

    if (lo) hbuf[tid] = (_Float16)0.0f;
    float c  = 0.0f;
    float hj = 0.0f;
    __syncthreads();

    const float* xb = x + (size_t)b * (T_ * I_);
    // 16-step x block = 256 floats; lane tid holds flat [4tid, 4tid+4)
    float4 xnext = *reinterpret_cast<const float4*>(xb + tid * 4);

    for (int tb = 0; tb < T_ / 16; ++tb) {
        half4_t xs;
        xs[0] = (_Float16)xnext.x; xs[1] = (_Float16)xnext.y;
        xs[2] = (_Float16)xnext.z; xs[3] = (_Float16)xnext.w;
        *reinterpret_cast<half4_t*>(&xbuf[tid * 4]) = xs;
        if (tb + 1 < T_ / 16) {
            xnext = *reinterpret_cast<const float4*>(xb + (tb + 1) * (16 * I_) + tid * 4);
        }
        __syncthreads();

#pragma unroll
        for (int tt = 0; tt < 16; ++tt) {
            // 4 independent accumulation chains, 12 deep each
            float aA0 = biasA, aA1 = 0.0f, aB0 = biasB, aB1 = 0.0f;

            H8 xv0, xv1;
            xv0.v = *reinterpret_cast<const half8_t*>(&xbuf[tt * I_]);
            xv1.v = *reinterpret_cast<const half8_t*>(&xbuf[tt * I_ + 8]);
#pragma unroll
            for (int k = 0; k < 4; ++k) {
                aA0 = __builtin_amdgcn_fdot2(xv0.h[k], wA[k], aA0, false);
                aB0 = __builtin_amdgcn_fdot2(xv0.h[k], wB[k], aB0, false);
                aA1 = __builtin_amdgcn_fdot2(xv1.h[k], wA[4 + k], aA1, false);
                aB1 = __builtin_amdgcn_fdot2(xv1.h[k], wB[4 + k], aB1, false);
            }
#pragma unroll
            for (int j8 = 0; j8 < 4; ++j8) {
                H8 hv;
                hv.v = *reinterpret_cast<const half8_t*>(&hbuf[j8 * 8]);
#pragma unroll
                for (int k = 0; k < 4; ++k) {
                    const int p = 8 + j8 * 4 + k;
                    if (j8 & 1) {
                        aA1 = __builtin_amdgcn_fdot2(hv.h[k], wA[p], aA1, false);
                        aB1 = __builtin_amdgcn_fdot2(hv.h[k], wB[p], aB1, false);
                    } else {
                        aA0 = __builtin_amdgcn_fdot2(hv.h[k], wA[p], aA0, false);
                        aB0 = __builtin_amdgcn_fdot2(hv.h[k], wB[p], aB0, false);
                    }
                }
            }
            const float aA = aA0 + aA1;
            const float aB = aB0 + aB1;

            // activations: A is always sigmoid; B is tanh (lanes<32) / sigmoid (>=32)
            const float actA = sigm_(aA);
            const float eB   = __builtin_amdgcn_exp2f(mB * aB);
            const float sB   = __builtin_amdgcn_rcpf(1.0f + eB);
            const float actB = __fmaf_rn(mulB, sB, addB);

            // half-wave exchange: lane j<32 receives sigm(f_j), sigm(o_j)
            const float xA = __shfl_xor(actA, 32, 64);
            const float xB = __shfl_xor(actB, 32, 64);

            if (lo) {
                c = __fmaf_rn(xA, c, actA * actB);   // f*c + i*g
                const float tc = tanh_(c);
                hj = xB * tc;                        // o * tanh(c)
                hbuf[tid] = (_Float16)hj;
            }
            __syncthreads();
        }
    }

    // ---- epilogue: out[b] = h_last . W_fc + b_fc ----
    float p = lo ? hj * Wfc[tid] : 0.0f;
#pragma unroll
    for (int off = 32; off > 0; off >>= 1) {
        p += __shfl_down(p, off, 64);
    }
    if (tid == 0) {
        out[b] = p + bfc[0];
    }
}

extern "C" void kernel_launch(void* const* d_in, const int* in_sizes, int n_in,
                              void* d_out, int out_size, void* d_ws, size_t ws_size,
                              hipStream_t stream) {
    const float* x   = (const float*)d_in[0];
    const float* Wih = (const float*)d_in[1];
    const float* Whh = (const float*)d_in[2];
    const float* bih = (const float*)d_in[3];
    const float* bhh = (const float*)d_in[4];
    const float* Wfc = (const float*)d_in[5];
    const float* bfc = (const float*)d_in[6];
    float* out = (float*)d_out;

    dim3 grid(B_);
    dim3 block(64);
    hipLaunchKernelGGL(lstm_gate_split, grid, block, 0, stream,
                       x, Wih, Whh, bih, bhh, Wfc, bfc, out);
}

// Round 6
// 226.729 us; speedup vs baseline: 1.1211x; 1.1211x over previous
//
#include <hip/hip_runtime.h>

#define B_ 4096
#define T_ 256
#define I_ 16
#define H_ 32

typedef _Float16 half2_t __attribute__((ext_vector_type(2)));
typedef _Float16 half8_t __attribute__((ext_vector_type(8)));

union H8 {
    half8_t v;
    half2_t h[4];
};

__device__ __forceinline__ float sigm_(float x) {
    float e = __builtin_amdgcn_exp2f(-1.442695041f * x);
    return __builtin_amdgcn_rcpf(1.0f + e);
}
__device__ __forceinline__ float tanh_(float x) {
    float e = __builtin_amdgcn_exp2f(-2.885390082f * x);
    float r = __builtin_amdgcn_rcpf(1.0f + e);
    return __fmaf_rn(2.0f, r, -1.0f);
}

// One 64-thread block = 1 wave = 2 batch elements (32 lanes each).
// Lane j owns h_j, c_j, computes gate rows {j,32+j,64+j,96+j} via f16 dot2.
// launch_bounds(64,1): let the allocator keep all 96 weight half2s in VGPRs
// (round-3's (64,4) cap produced VGPR=64 + 2MB of spill traffic/dispatch).
// NO per-step barrier: 1-wave block is lockstep; same-wave DS ops are in-order,
// so h ds_write -> next-step ds_read is safe with compiler-inserted lgkmcnt.
// One barrier per 16-step x-staging chunk (amortizes the vmcnt drain 16x).
__global__ __launch_bounds__(64, 1)
void lstm_v5(const float* __restrict__ x,
             const float* __restrict__ Wih,
             const float* __restrict__ Whh,
             const float* __restrict__ bih,
             const float* __restrict__ bhh,
             const float* __restrict__ Wfc,
             const float* __restrict__ bfc,
             float* __restrict__ out)
{
    __shared__ __align__(16) _Float16 hbuf[2][H_];          // 128 B
    __shared__ __align__(16) _Float16 xbuf[2][16 * I_];     // 1 KB (16 timesteps)

    const int tid  = threadIdx.x;
    const int elem = tid >> 5;
    const int idx  = tid & 31;
    const int b    = blockIdx.x * 2 + elem;

    // ---- load + f16-pack per-lane weight rows (resident in VGPRs) ----
    half2_t wih2[4][I_ / 2];   // 32 VGPR
    half2_t whh2[4][H_ / 2];   // 64 VGPR
    float bias[4];
#pragma unroll
    for (int q = 0; q < 4; ++q) {
        const int row = q * 32 + idx;   // gate order i,f,g,o
        const float4* pih = reinterpret_cast<const float4*>(Wih + row * I_);
#pragma unroll
        for (int k = 0; k < I_ / 4; ++k) {
            const float4 v = pih[k];
            wih2[q][2 * k + 0] = half2_t{(_Float16)v.x, (_Float16)v.y};
            wih2[q][2 * k + 1] = half2_t{(_Float16)v.z, (_Float16)v.w};
        }
        const float4* phh = reinterpret_cast<const float4*>(Whh + row * H_);
#pragma unroll
        for (int k = 0; k < H_ / 4; ++k) {
            const float4 v = phh[k];
            whh2[q][2 * k + 0] = half2_t{(_Float16)v.x, (_Float16)v.y};
            whh2[q][2 * k + 1] = half2_t{(_Float16)v.z, (_Float16)v.w};
        }
        bias[q] = bih[row] + bhh[row];
    }

    hbuf[elem][idx] = (_Float16)0.0f;
    float c  = 0.0f;
    float hj = 0.0f;

    const float* xb = x + (size_t)b * (T_ * I_);
    // 16-step chunk = 256 floats/elem; lane idx covers flat [8*idx, 8*idx+8)
    float4 xn0 = *reinterpret_cast<const float4*>(xb + 8 * idx);
    float4 xn1 = *reinterpret_cast<const float4*>(xb + 8 * idx + 4);

    for (int tb = 0; tb < T_ / 16; ++tb) {
        // stage prefetched chunk as f16 (one ds_write_b128/lane)
        H8 xs;
        xs.h[0] = half2_t{(_Float16)xn0.x, (_Float16)xn0.y};
        xs.h[1] = half2_t{(_Float16)xn0.z, (_Float16)xn0.w};
        xs.h[2] = half2_t{(_Float16)xn1.x, (_Float16)xn1.y};
        xs.h[3] = half2_t{(_Float16)xn1.z, (_Float16)xn1.w};
        *reinterpret_cast<half8_t*>(&xbuf[elem][8 * idx]) = xs.v;
        if (tb + 1 < T_ / 16) {
            const float* nx = xb + (tb + 1) * (16 * I_) + 8 * idx;
            xn0 = *reinterpret_cast<const float4*>(nx);
            xn1 = *reinterpret_cast<const float4*>(nx + 4);
        }
        __syncthreads();   // once per 16 steps (also covers x prefetch drain)

#pragma unroll
        for (int tt = 0; tt < 16; ++tt) {
            float ai = bias[0], af = bias[1], ag = bias[2], ao = bias[3];

            // x contribution: 16 dims = 8 half2 (2x ds_read_b128, broadcast)
            H8 xv0, xv1;
            xv0.v = *reinterpret_cast<const half8_t*>(&xbuf[elem][tt * I_]);
            xv1.v = *reinterpret_cast<const half8_t*>(&xbuf[elem][tt * I_ + 8]);
#pragma unroll
            for (int k = 0; k < 4; ++k) {
                ai = __builtin_amdgcn_fdot2(xv0.h[k], wih2[0][k], ai, false);
                af = __builtin_amdgcn_fdot2(xv0.h[k], wih2[1][k], af, false);
                ag = __builtin_amdgcn_fdot2(xv0.h[k], wih2[2][k], ag, false);
                ao = __builtin_amdgcn_fdot2(xv0.h[k], wih2[3][k], ao, false);
            }
#pragma unroll
            for (int k = 0; k < 4; ++k) {
                ai = __builtin_amdgcn_fdot2(xv1.h[k], wih2[0][4 + k], ai, false);
                af = __builtin_amdgcn_fdot2(xv1.h[k], wih2[1][4 + k], af, false);
                ag = __builtin_amdgcn_fdot2(xv1.h[k], wih2[2][4 + k], ag, false);
                ao = __builtin_amdgcn_fdot2(xv1.h[k], wih2[3][4 + k], ao, false);
            }

            // h contribution: 32 dims = 16 half2 (4x ds_read_b128, broadcast)
#pragma unroll
            for (int j8 = 0; j8 < 4; ++j8) {
                H8 hv;
                hv.v = *reinterpret_cast<const half8_t*>(&hbuf[elem][j8 * 8]);
#pragma unroll
                for (int k = 0; k < 4; ++k) {
                    const int p = j8 * 4 + k;
                    ai = __builtin_amdgcn_fdot2(hv.h[k], whh2[0][p], ai, false);
                    af = __builtin_amdgcn_fdot2(hv.h[k], whh2[1][p], af, false);
                    ag = __builtin_amdgcn_fdot2(hv.h[k], whh2[2][p], ag, false);
                    ao = __builtin_amdgcn_fdot2(hv.h[k], whh2[3][p], ao, false);
                }
            }

            const float gi = sigm_(ai);
            const float gf = sigm_(af);
            const float gg = tanh_(ag);
            const float go = sigm_(ao);

            c  = __fmaf_rn(gf, c, gi * gg);
            hj = go * tanh_(c);

            // lockstep wave: all lanes' reads above issued before this write;
            // same-wave DS ops complete in order -> no barrier needed.
            hbuf[elem][idx] = (_Float16)hj;
        }
    }

    // ---- epilogue: out[b] = h_last . W_fc + b_fc ----
    float p = hj * Wfc[idx];
#pragma unroll
    for (int off = 16; off > 0; off >>= 1) {
        p += __shfl_down(p, off, 32);
    }
    if (idx == 0) {
        out[b] = p + bfc[0];
    }
}

extern "C" void kernel_launch(void* const* d_in, const int* in_sizes, int n_in,
                              void* d_out, int out_size, void* d_ws, size_t ws_size,
                              hipStream_t stream) {
    const float* x   = (const float*)d_in[0];
    const float* Wih = (const float*)d_in[1];
    const float* Whh = (const float*)d_in[2];
    const float* bih = (const float*)d_in[3];
    const float* bhh = (const float*)d_in[4];
    const float* Wfc = (const float*)d_in[5];
    const float* bfc = (const float*)d_in[6];
    float* out = (float*)d_out;

    dim3 grid(B_ / 2);
    dim3 block(64);
    hipLaunchKernelGGL(lstm_v5, grid, block, 0, stream,
                       x, Wih, Whh, bih, bhh, Wfc, bfc, out);
}